// Round 1
// baseline (325.662 us; speedup 1.0000x reference)
//
#include <hip/hip_runtime.h>

#define FSIZE   768
#define TW0     769
#define TW1     193
#define COL1    576
#define NPAIRS  300000

__device__ __forceinline__ float loss_term(float x, float y) {
    // logaddexp(0, x) - x*y = max(x,0) + log1p(exp(-|x|)) - x*y
    float ax = fabsf(x);
    return fmaxf(x, 0.0f) + log1pf(__expf(-ax)) - x * y;
}

// Task 0: one 64-lane wave per pair. dot(feat[r][0:768], w0[c][0:768]) + w0[c][768]
__global__ __launch_bounds__(256) void task0_kernel(
    const float* __restrict__ feat, const float* __restrict__ wt,
    const int* __restrict__ idx, const float* __restrict__ y,
    float* __restrict__ out_final, float* __restrict__ partial)
{
    __shared__ float lsum[4];
    const int lane = threadIdx.x & 63;
    const int wv   = threadIdx.x >> 6;
    const int pair = blockIdx.x * 4 + wv;

    const int r = idx[2 * pair];
    const int c = idx[2 * pair + 1];
    const float4* f4   = (const float4*)(feat + (size_t)r * FSIZE);
    const float*  wrow = wt + (size_t)c * TW0;

    float s = 0.0f;
#pragma unroll
    for (int k = 0; k < 3; ++k) {
        const int j = lane + (k << 6);          // float4 index, 0..191
        float4 f = f4[j];
        s += f.x * wrow[4 * j + 0] + f.y * wrow[4 * j + 1]
           + f.z * wrow[4 * j + 2] + f.w * wrow[4 * j + 3];
    }
#pragma unroll
    for (int m = 32; m; m >>= 1) s += __shfl_xor(s, m, 64);

    if (lane == 0) {
        const float logit = s + wrow[FSIZE];    // bias weight (feature bias = 1.0)
        out_final[pair] = logit;
        lsum[wv] = loss_term(logit, y[pair]);
    }
    __syncthreads();
    if (threadIdx.x == 0)
        partial[blockIdx.x] = lsum[0] + lsum[1] + lsum[2] + lsum[3];
}

// Task 1: 16 lanes per pair (4 pairs/wave). dot(feat[r][576:768], w1[c][0:192]) + w1[c][192]
__global__ __launch_bounds__(256) void task1_kernel(
    const float* __restrict__ feat, const float* __restrict__ wt,
    const int* __restrict__ idx, const float* __restrict__ y,
    float* __restrict__ partial)
{
    __shared__ float lsum[16];
    const int lane = threadIdx.x & 63;
    const int wv   = threadIdx.x >> 6;
    const int sub  = lane & 15;
    const int pg   = lane >> 4;
    const int pair = (blockIdx.x * 4 + wv) * 4 + pg;

    const int r = idx[2 * pair];
    const int c = idx[2 * pair + 1];
    const float4* f4   = (const float4*)(feat + (size_t)r * FSIZE + COL1);
    const float*  wrow = wt + (size_t)c * TW1;

    float s = 0.0f;
#pragma unroll
    for (int k = 0; k < 3; ++k) {
        const int j = sub + (k << 4);           // float4 index, 0..47
        float4 f = f4[j];
        s += f.x * wrow[4 * j + 0] + f.y * wrow[4 * j + 1]
           + f.z * wrow[4 * j + 2] + f.w * wrow[4 * j + 3];
    }
#pragma unroll
    for (int m = 8; m; m >>= 1) s += __shfl_xor(s, m, 64);

    if (sub == 0) {
        const float logit = s + wrow[TW1 - 1];
        lsum[wv * 4 + pg] = loss_term(logit, y[pair]);
    }
    __syncthreads();
    if (threadIdx.x == 0) {
        float t = 0.0f;
#pragma unroll
        for (int i = 0; i < 16; ++i) t += lsum[i];
        partial[blockIdx.x] = t;
    }
}

__global__ __launch_bounds__(1024) void reduce_kernel(
    const float* __restrict__ partial, int n, float* __restrict__ out)
{
    __shared__ float sh[1024];
    float s = 0.0f;
    for (int i = threadIdx.x; i < n; i += 1024) s += partial[i];
    sh[threadIdx.x] = s;
    __syncthreads();
    for (int off = 512; off; off >>= 1) {
        if ((int)threadIdx.x < off) sh[threadIdx.x] += sh[threadIdx.x + off];
        __syncthreads();
    }
    if (threadIdx.x == 0) out[0] = sh[0];
}

extern "C" void kernel_launch(void* const* d_in, const int* in_sizes, int n_in,
                              void* d_out, int out_size, void* d_ws, size_t ws_size,
                              hipStream_t stream) {
    const float* feat = (const float*)d_in[0];   // 16*512*768
    const float* w0   = (const float*)d_in[1];   // 30000*769
    const float* w1   = (const float*)d_in[2];   // 30000*193
    const int*   idx0 = (const int*)d_in[3];     // 300000*2 (int32)
    const float* y0   = (const float*)d_in[4];
    // d_in[5] = seen0 (unused)
    const int*   idx1 = (const int*)d_in[6];
    const float* y1   = (const float*)d_in[7];
    // d_in[8] = seen1 (unused)

    float* out     = (float*)d_out;              // [0..299999]=final, [300000]=loss
    float* partial = (float*)d_ws;

    const int nb0 = NPAIRS / 4;    // 75000 blocks, 4 pairs each
    const int nb1 = NPAIRS / 16;   // 18750 blocks, 16 pairs each

    task0_kernel<<<nb0, 256, 0, stream>>>(feat, w0, idx0, y0, out, partial);
    task1_kernel<<<nb1, 256, 0, stream>>>(feat, w1, idx1, y1, partial + nb0);
    reduce_kernel<<<1, 1024, 0, stream>>>(partial, nb0 + nb1, out + NPAIRS);
}

// Round 2
// 269.729 us; speedup vs baseline: 1.2074x; 1.2074x over previous
//
#include <hip/hip_runtime.h>

#define FSIZE   768
#define TW0     769
#define TW1     193
#define COL1    576
#define NPAIRS  300000
#define NCODES  30000
#define CHUNK   16
#define NWAVES0 (NPAIRS / CHUNK)            // 18750
#define NB0     ((NWAVES0 + 3) / 4)         // 4688 blocks, 4 waves each
#define NWAVES0_PAD (NB0 * 4)               // 18752
#define NB1     (NPAIRS / 16)               // 18750 blocks for task1

// ws layout (bytes)
#define WS_CNT     0
#define WS_CURSOR  120000
#define WS_SORTED  240000
#define WS_PARTIAL 1440000
#define NPARTIAL   (NWAVES0_PAD + NB1)      // 18752 + 18750 = 37502
#define WS_NEEDED  (WS_PARTIAL + NPARTIAL * 4)

__device__ __forceinline__ float loss_term(float x, float y) {
    float ax = fabsf(x);
    return fmaxf(x, 0.0f) + log1pf(__expf(-ax)) - x * y;
}

// 16B load from a 4B-aligned address (compiler emits dwordx4 if HW allows, else dwords)
__device__ __forceinline__ float4 ld4u(const float* p) {
    float4 v; __builtin_memcpy(&v, p, 16); return v;
}

__global__ __launch_bounds__(256) void zero_cnt_kernel(int* __restrict__ cnt) {
    int i = blockIdx.x * 256 + threadIdx.x;
    if (i < NCODES) cnt[i] = 0;
}

__global__ __launch_bounds__(256) void hist_kernel(const int* __restrict__ idx,
                                                   int* __restrict__ cnt) {
    int p = blockIdx.x * 256 + threadIdx.x;
    if (p < NPAIRS) atomicAdd(&cnt[idx[2 * p + 1]], 1);
}

__global__ __launch_bounds__(1024) void scan_kernel(const int* __restrict__ cnt,
                                                    int* __restrict__ cursor) {
    __shared__ int sh[1024];
    const int t = threadIdx.x;
    const int base = t * 30;
    int local[30];
    int s = 0;
#pragma unroll
    for (int j = 0; j < 30; ++j) {
        int v = (base + j < NCODES) ? cnt[base + j] : 0;
        local[j] = s; s += v;
    }
    sh[t] = s;
    __syncthreads();
    for (int off = 1; off < 1024; off <<= 1) {
        int v = (t >= off) ? sh[t - off] : 0;
        __syncthreads();
        sh[t] += v;
        __syncthreads();
    }
    const int chunkbase = sh[t] - s;   // exclusive prefix for this thread's chunk
#pragma unroll
    for (int j = 0; j < 30; ++j)
        if (base + j < NCODES) cursor[base + j] = chunkbase + local[j];
}

__global__ __launch_bounds__(256) void scatter_kernel(const int* __restrict__ idx,
                                                      int* __restrict__ cursor,
                                                      int* __restrict__ sorted) {
    int p = blockIdx.x * 256 + threadIdx.x;
    if (p < NPAIRS) {
        int c = idx[2 * p + 1];
        int pos = atomicAdd(&cursor[c], 1);
        sorted[pos] = p;
    }
}

// Task 0 main: one wave per CHUNK sorted pairs; weight row cached in VGPRs across
// same-code runs; features streamed as aligned float4.
__global__ __launch_bounds__(256) void task0_sorted_kernel(
    const float* __restrict__ feat, const float* __restrict__ wt,
    const int* __restrict__ idx, const float* __restrict__ y,
    const int* __restrict__ sorted,
    float* __restrict__ out_final, float* __restrict__ partial)
{
    const int lane = threadIdx.x & 63;
    const int wid = blockIdx.x * 4 + (threadIdx.x >> 6);
    if (wid >= NWAVES0) { if (lane == 0) partial[wid] = 0.0f; return; }
    const int base = wid * CHUNK;

    // prefetch chunk metadata into lanes: slot j lives at lanes j, 16+j, 32+j
    const int pb = sorted[base + (lane & 15)];
    const int sel = lane >> 4;
    int g;
    if (sel == 0)      g = idx[2 * pb];                     // r
    else if (sel == 1) g = idx[2 * pb + 1];                 // c
    else if (sel == 2) g = __float_as_int(y[pb]);           // y
    else               g = 0;

    float lossacc = 0.0f;
    int prev_c = -1;
    float4 w0, w1, w2; float wb = 0.0f;

    for (int i = 0; i < CHUNK; ++i) {
        const int r = __shfl(g, i, 64);
        const int c = __shfl(g, 16 + i, 64);
        const float yv = __int_as_float(__shfl(g, 32 + i, 64));

        if (c != prev_c) {                    // wave-uniform branch
            prev_c = c;
            const float* wrow = wt + (size_t)c * TW0;
            w0 = ld4u(wrow + 4 * lane);
            w1 = ld4u(wrow + 4 * lane + 256);
            w2 = ld4u(wrow + 4 * lane + 512);
            wb = wrow[FSIZE];
        }
        const float4* f4 = (const float4*)(feat + (size_t)r * FSIZE);
        const float4 a0 = f4[lane], a1 = f4[lane + 64], a2 = f4[lane + 128];

        float s = a0.x * w0.x + a0.y * w0.y + a0.z * w0.z + a0.w * w0.w
                + a1.x * w1.x + a1.y * w1.y + a1.z * w1.z + a1.w * w1.w
                + a2.x * w2.x + a2.y * w2.y + a2.z * w2.z + a2.w * w2.w;
#pragma unroll
        for (int m = 32; m; m >>= 1) s += __shfl_xor(s, m, 64);

        const float logit = s + wb;
        lossacc += loss_term(logit, yv);
        if (lane == 0) out_final[__shfl(pb, i, 64)] = logit;
    }
    if (lane == 0) partial[wid] = lossacc;
}

// ---------------- fallback (unsorted) task0, used only if ws too small ----------------
__global__ __launch_bounds__(256) void task0_kernel(
    const float* __restrict__ feat, const float* __restrict__ wt,
    const int* __restrict__ idx, const float* __restrict__ y,
    float* __restrict__ out_final, float* __restrict__ partial)
{
    __shared__ float lsum[4];
    const int lane = threadIdx.x & 63;
    const int wv = threadIdx.x >> 6;
    const int pair = blockIdx.x * 4 + wv;
    const int r = idx[2 * pair];
    const int c = idx[2 * pair + 1];
    const float4* f4 = (const float4*)(feat + (size_t)r * FSIZE);
    const float* wrow = wt + (size_t)c * TW0;
    float s = 0.0f;
#pragma unroll
    for (int k = 0; k < 3; ++k) {
        const int j = lane + (k << 6);
        float4 f = f4[j];
        float4 w = ld4u(wrow + 4 * j);
        s += f.x * w.x + f.y * w.y + f.z * w.z + f.w * w.w;
    }
#pragma unroll
    for (int m = 32; m; m >>= 1) s += __shfl_xor(s, m, 64);
    if (lane == 0) {
        const float logit = s + wrow[FSIZE];
        out_final[pair] = logit;
        lsum[wv] = loss_term(logit, y[pair]);
    }
    __syncthreads();
    if (threadIdx.x == 0)
        partial[blockIdx.x] = lsum[0] + lsum[1] + lsum[2] + lsum[3];
}

// Task 1: 16 lanes per pair (4 pairs/wave), wide loads on both sides
__global__ __launch_bounds__(256) void task1_kernel(
    const float* __restrict__ feat, const float* __restrict__ wt,
    const int* __restrict__ idx, const float* __restrict__ y,
    float* __restrict__ partial)
{
    __shared__ float lsum[16];
    const int lane = threadIdx.x & 63;
    const int wv = threadIdx.x >> 6;
    const int sub = lane & 15;
    const int pg = lane >> 4;
    const int pair = (blockIdx.x * 4 + wv) * 4 + pg;

    const int r = idx[2 * pair];
    const int c = idx[2 * pair + 1];
    const float4* f4 = (const float4*)(feat + (size_t)r * FSIZE + COL1);
    const float* wrow = wt + (size_t)c * TW1;

    float s = 0.0f;
#pragma unroll
    for (int k = 0; k < 3; ++k) {
        const int j = sub + (k << 4);
        float4 f = f4[j];
        float4 w = ld4u(wrow + 4 * j);
        s += f.x * w.x + f.y * w.y + f.z * w.z + f.w * w.w;
    }
#pragma unroll
    for (int m = 8; m; m >>= 1) s += __shfl_xor(s, m, 64);

    if (sub == 0) {
        const float logit = s + wrow[TW1 - 1];
        lsum[wv * 4 + pg] = loss_term(logit, y[pair]);
    }
    __syncthreads();
    if (threadIdx.x == 0) {
        float t = 0.0f;
#pragma unroll
        for (int i = 0; i < 16; ++i) t += lsum[i];
        partial[blockIdx.x] = t;
    }
}

__global__ __launch_bounds__(1024) void reduce_kernel(
    const float* __restrict__ partial, int n, float* __restrict__ out)
{
    __shared__ float sh[1024];
    float s = 0.0f;
    for (int i = threadIdx.x; i < n; i += 1024) s += partial[i];
    sh[threadIdx.x] = s;
    __syncthreads();
    for (int off = 512; off; off >>= 1) {
        if ((int)threadIdx.x < off) sh[threadIdx.x] += sh[threadIdx.x + off];
        __syncthreads();
    }
    if (threadIdx.x == 0) out[0] = sh[0];
}

extern "C" void kernel_launch(void* const* d_in, const int* in_sizes, int n_in,
                              void* d_out, int out_size, void* d_ws, size_t ws_size,
                              hipStream_t stream) {
    const float* feat = (const float*)d_in[0];
    const float* w0   = (const float*)d_in[1];
    const float* w1   = (const float*)d_in[2];
    const int*   idx0 = (const int*)d_in[3];
    const float* y0   = (const float*)d_in[4];
    const int*   idx1 = (const int*)d_in[6];
    const float* y1   = (const float*)d_in[7];

    float* out = (float*)d_out;
    char* ws = (char*)d_ws;

    if (ws_size >= (size_t)WS_NEEDED) {
        int* cnt      = (int*)(ws + WS_CNT);
        int* cursor   = (int*)(ws + WS_CURSOR);
        int* sorted   = (int*)(ws + WS_SORTED);
        float* part   = (float*)(ws + WS_PARTIAL);

        zero_cnt_kernel<<<(NCODES + 255) / 256, 256, 0, stream>>>(cnt);
        hist_kernel<<<(NPAIRS + 255) / 256, 256, 0, stream>>>(idx0, cnt);
        scan_kernel<<<1, 1024, 0, stream>>>(cnt, cursor);
        scatter_kernel<<<(NPAIRS + 255) / 256, 256, 0, stream>>>(idx0, cursor, sorted);
        task0_sorted_kernel<<<NB0, 256, 0, stream>>>(feat, w0, idx0, y0, sorted,
                                                     out, part);
        task1_kernel<<<NB1, 256, 0, stream>>>(feat, w1, idx1, y1, part + NWAVES0_PAD);
        reduce_kernel<<<1, 1024, 0, stream>>>(part, NPARTIAL, out + NPAIRS);
    } else {
        // fallback: unsorted path (needs 375 KB)
        float* part = (float*)ws;
        const int nb0 = NPAIRS / 4;
        task0_kernel<<<nb0, 256, 0, stream>>>(feat, w0, idx0, y0, out, part);
        task1_kernel<<<NB1, 256, 0, stream>>>(feat, w1, idx1, y1, part + nb0);
        reduce_kernel<<<1, 1024, 0, stream>>>(part, nb0 + NB1, out + NPAIRS);
    }
}